// Round 2
// baseline (872.937 us; speedup 1.0000x reference)
//
#include <hip/hip_runtime.h>
#include <hip/hip_bf16.h>
#include <hip/hip_fp16.h>

#define H 2048
#define E 8
#define DFF 8192
#define NTOK 4096
#define NB 4  // H/512 scale blocks

typedef _Float16 f16x8 __attribute__((ext_vector_type(8)));
typedef float f32x4 __attribute__((ext_vector_type(4)));

#define AS1 __attribute__((address_space(1)))
#define AS3 __attribute__((address_space(3)))

__device__ __forceinline__ void gl_lds16(const void* g, void* l) {
    __builtin_amdgcn_global_load_lds((const AS1 unsigned int*)g,
                                     (AS3 unsigned int*)l, 16, 0, 0);
}

__device__ __forceinline__ float gelu_f(float x) {
    float u = 0.7978845608028654f * x * (1.0f + 0.044715f * x * x);
    float t = fabsf(u);
    float e = __expf(-2.0f * t);
    float th = (1.0f - e) / (1.0f + e);
    th = copysignf(th, u);
    return 0.5f * x * (1.0f + th);
}

// ---------------- router (fp32) + x -> fp16 cast ----------------
__global__ __launch_bounds__(256) void router_cast_kernel(
    const float* __restrict__ x, const float* __restrict__ rw,
    float* __restrict__ probs, _Float16* __restrict__ xh)
{
    int n = blockIdx.x, t = threadIdx.x;
    float acc[E];
#pragma unroll
    for (int e = 0; e < E; ++e) acc[e] = 0.f;
    const float* xr = x + (size_t)n * H;
#pragma unroll
    for (int k = 0; k < H / 256; ++k) {
        int h = t + k * 256;
        float xv = xr[h];
        xh[(size_t)n * H + h] = (_Float16)xv;
        const float4* r4 = reinterpret_cast<const float4*>(rw + (size_t)h * E);
        float4 a = r4[0], b = r4[1];
        acc[0] += xv * a.x; acc[1] += xv * a.y; acc[2] += xv * a.z; acc[3] += xv * a.w;
        acc[4] += xv * b.x; acc[5] += xv * b.y; acc[6] += xv * b.z; acc[7] += xv * b.w;
    }
#pragma unroll
    for (int e = 0; e < E; ++e) {
        float v = acc[e];
#pragma unroll
        for (int o = 32; o > 0; o >>= 1) v += __shfl_down(v, o, 64);
        acc[e] = v;
    }
    __shared__ float red[4][E];
    int wave = t >> 6, lane = t & 63;
    if (lane == 0) {
#pragma unroll
        for (int e = 0; e < E; ++e) red[wave][e] = acc[e];
    }
    __syncthreads();
    if (t == 0) {
        float lg[E];
        float mx = -1e30f;
#pragma unroll
        for (int e = 0; e < E; ++e) {
            lg[e] = red[0][e] + red[1][e] + red[2][e] + red[3][e];
            mx = fmaxf(mx, lg[e]);
        }
        float s = 0.f;
#pragma unroll
        for (int e = 0; e < E; ++e) { lg[e] = expf(lg[e] - mx); s += lg[e]; }
        float inv = 1.f / s;
#pragma unroll
        for (int e = 0; e < E; ++e) {
            float p = lg[e] * inv;
            p = __half2float(__float2half(p));
            probs[(size_t)n * E + e] = p;
        }
    }
}

// ---------------- transpose + cast fp32 [R,C] -> fp16 [C,R] ----------------
__global__ __launch_bounds__(256) void transpose_cast_kernel(
    const float* __restrict__ src, _Float16* __restrict__ dst, int R, int C)
{
    __shared__ float tile[32][33];
    int tx = threadIdx.x & 31, ty = threadIdx.x >> 5;
    int c0 = blockIdx.x * 32, r0 = blockIdx.y * 32;
#pragma unroll
    for (int i = ty; i < 32; i += 8)
        tile[i][tx] = src[(size_t)(r0 + i) * C + c0 + tx];
    __syncthreads();
#pragma unroll
    for (int i = ty; i < 32; i += 8)
        dst[(size_t)(c0 + i) * R + r0 + tx] = (_Float16)tile[tx][i];
}

// ---------------- NF4 dequant + expert mix -> moe (fp32) ----------------
__global__ __launch_bounds__(256) void moe_kernel(
    const int* __restrict__ nf4, const float* __restrict__ mean,
    const float* __restrict__ stdv, const float* __restrict__ cb,
    const float* __restrict__ probs, float* __restrict__ moe)
{
    int n = blockIdx.x, t = threadIdx.x;
    __shared__ float cbl[32];
    __shared__ float ps[E][NB];
    __shared__ float cmean[NB];
    if (t < 16) { float v = cb[t]; cbl[t] = v; cbl[t + 16] = v; }
    else if (t >= 32 && t < 64) {
        int e = (t - 32) >> 2, b = t & 3;
        ps[e][b] = probs[(size_t)n * E + e] * stdv[((size_t)n * E + e) * NB + b];
    } else if (t >= 64 && t < 68) {
        int b = t - 64; float s = 0.f;
        for (int e = 0; e < E; ++e)
            s += probs[(size_t)n * E + e] * mean[((size_t)n * E + e) * NB + b];
        cmean[b] = s;
    }
    __syncthreads();
    int cboff = (t & 1) << 4;
    const int* w = nf4 + (size_t)n * (E * H / 2);
    float2* outp = reinterpret_cast<float2*>(moe + (size_t)n * H);
#pragma unroll
    for (int k = 0; k < 4; ++k) {
        int j = t + k * 256;
        float psr[E];
#pragma unroll
        for (int e = 0; e < E; ++e) psr[e] = ps[e][k];
        float cm = cmean[k];
        float aL = cm, aH = cm;
#pragma unroll
        for (int e = 0; e < E; ++e) {
            int word = w[e * (H / 2) + j];
            aL += psr[e] * cbl[(word & 15) + cboff];
            aH += psr[e] * cbl[((word >> 4) & 15) + cboff];
        }
        outp[j] = make_float2(aL, aH);
    }
}

// ---------------- fp16 MFMA GEMM, 256x128 tile, triple-buffered ----------
// C = A[M,K] * Bt[N,K]^T.  512 threads / 8 waves (4M x 2N, per-wave 64x64),
// BK=64, THREE LDS buffers of 48 KB (144 KB): iteration k stages tile k+2,
// so every staged load has a full 8-phase (~2 K-tile) landing window and the
// per-K-tile wait is a single counted vmcnt(6) (never 0 in steady state).
// k-seg-major LDS layout (bank-conflict-free; staging permutation done via
// per-lane GLOBAL addresses so global_load_lds writes linearly).
// Per K-tile, 4 phases, Gray-ordered C-quadrants; each phase:
//   { ds_read fragment group (reads BEFORE the barrier -> latency hides in
//     barrier skew); issue stage loads; s_barrier; lgkmcnt(0); setprio(1);
//     8 MFMA; setprio(0); s_barrier }
//   p0: read aL,bL  | stage A0,A1 | mfma aL*bL -> acc[0:2][0:2]
//   p1: read bH     | stage A2,A3 | mfma aL*bH -> acc[0:2][2:4]
//   p2: read aH     | stage B0,B1 | mfma aH*bH -> acc[2:4][2:4]
//   p3: (no reads; bL live)       | mfma aH*bL -> acc[2:4][0:2]; vmcnt(6); bar
// EPI 0: out = f16(gelu(acc));  EPI 1: out = acc + addsrc (float).
template <int EPI, typename OT>
__global__ __launch_bounds__(512, 2) void gemm256_kernel(
    const _Float16* __restrict__ A, const _Float16* __restrict__ Bt,
    const float* __restrict__ addsrc, OT* __restrict__ outb,
    int K, int N, int bwShift)
{
    constexpr int BM = 256;
    constexpr int BN = 128;
    constexpr int BK = 64;
    constexpr unsigned ASZ = BM * BK * 2;      // 32 KB
    constexpr unsigned BSZ = BN * BK * 2;      // 16 KB
    constexpr unsigned BUFSZ = ASZ + BSZ;      // 48 KB
    constexpr unsigned LDSTOT = 3 * BUFSZ;     // 144 KB

    __shared__ uint4 lds_u4[LDSTOT / 16];
    char* lds = (char*)lds_u4;

    int t = threadIdx.x;
    int id = blockIdx.x;
    int xcd = id & 7, chunk = id >> 3;
    int bx = (xcd << bwShift) | (chunk & ((1 << bwShift) - 1));
    int by = chunk >> bwShift;
    int m0 = by * BM, n0 = bx * BN;

    // staging source pointers (units: halves).  LDS 16B-chunk (s*512 + t)
    // holds (kseg, row) with row = t & (ROWS-1); source addr reproduces it.
    const unsigned short* sA = (const unsigned short*)A
        + (size_t)(m0 + (t & 255)) * K + (t >> 8) * 8;
    const unsigned short* sB = (const unsigned short*)Bt
        + (size_t)(n0 + (t & 127)) * K + (t >> 7) * 8;
    unsigned dstT = (unsigned)t * 16;

    int lane = t & 63, wave = t >> 6;
    int wr = wave >> 1, wc = wave & 1;
    int mb = wr * 64, nb = wc * 64;
    int q = lane >> 4, m16 = lane & 15;

    f32x4 acc[4][4] = {};
    f16x8 af[4];   // current A half (2 i-frags x 2 kh); aL then overwritten by aH
    f16x8 bL[4];   // B cols 0-31 of wave  (2 j x 2 kh) — lives全 K-tile
    f16x8 bH[4];   // B cols 32-63 of wave

    // prologue: stage tile 0 -> buf0, tile 1 -> buf1
#pragma unroll
    for (int tl = 0; tl < 2; ++tl) {
        char* W = lds + tl * BUFSZ;
#pragma unroll
        for (int s = 0; s < 4; ++s)
            gl_lds16(sA + tl * BK + s * 16, W + s * 8192 + dstT);
#pragma unroll
        for (int s = 0; s < 2; ++s)
            gl_lds16(sB + tl * BK + s * 32, W + ASZ + s * 8192 + dstT);
    }
    asm volatile("s_waitcnt vmcnt(6)" ::: "memory");  // tile 0 landed
    asm volatile("s_barrier" ::: "memory");

    unsigned cur = 0;
    for (int k0 = 0; k0 < K; k0 += BK) {
        char* R = lds + cur;
        unsigned stg = cur + 2 * BUFSZ;
        if (stg >= LDSTOT) stg -= LDSTOT;
        char* W = lds + stg;
        bool st = (k0 + 2 * BK) < K;   // stage tile k+2 this iteration
        int ks = k0 + 2 * BK;

        // ---------------- phase 0: aL, bL ----------------
#pragma unroll
        for (int il = 0; il < 2; ++il)
#pragma unroll
            for (int kh = 0; kh < 2; ++kh)
                af[il * 2 + kh] = *(const f16x8*)(R +
                    (unsigned)((kh * 4 + q) * BM + mb + il * 16 + m16) * 16u);
#pragma unroll
        for (int jl = 0; jl < 2; ++jl)
#pragma unroll
            for (int kh = 0; kh < 2; ++kh)
                bL[jl * 2 + kh] = *(const f16x8*)(R + ASZ +
                    (unsigned)((kh * 4 + q) * BN + nb + jl * 16 + m16) * 16u);
        if (st) {
            gl_lds16(sA + ks,      W + dstT);
            gl_lds16(sA + ks + 16, W + 8192 + dstT);
        }
        asm volatile("s_barrier" ::: "memory");
        asm volatile("s_waitcnt lgkmcnt(0)" ::: "memory");
        __builtin_amdgcn_s_setprio(1);
#pragma unroll
        for (int il = 0; il < 2; ++il)
#pragma unroll
            for (int jl = 0; jl < 2; ++jl)
#pragma unroll
                for (int kh = 0; kh < 2; ++kh)
                    acc[il][jl] = __builtin_amdgcn_mfma_f32_16x16x32_f16(
                        af[il * 2 + kh], bL[jl * 2 + kh], acc[il][jl], 0, 0, 0);
        __builtin_amdgcn_s_setprio(0);
        asm volatile("s_barrier" ::: "memory");

        // ---------------- phase 1: bH ----------------
#pragma unroll
        for (int jl = 0; jl < 2; ++jl)
#pragma unroll
            for (int kh = 0; kh < 2; ++kh)
                bH[jl * 2 + kh] = *(const f16x8*)(R + ASZ +
                    (unsigned)((kh * 4 + q) * BN + nb + (2 + jl) * 16 + m16) * 16u);
        if (st) {
            gl_lds16(sA + ks + 32, W + 2 * 8192 + dstT);
            gl_lds16(sA + ks + 48, W + 3 * 8192 + dstT);
        }
        asm volatile("s_barrier" ::: "memory");
        asm volatile("s_waitcnt lgkmcnt(0)" ::: "memory");
        __builtin_amdgcn_s_setprio(1);
#pragma unroll
        for (int il = 0; il < 2; ++il)
#pragma unroll
            for (int jl = 0; jl < 2; ++jl)
#pragma unroll
                for (int kh = 0; kh < 2; ++kh)
                    acc[il][2 + jl] = __builtin_amdgcn_mfma_f32_16x16x32_f16(
                        af[il * 2 + kh], bH[jl * 2 + kh], acc[il][2 + jl], 0, 0, 0);
        __builtin_amdgcn_s_setprio(0);
        asm volatile("s_barrier" ::: "memory");

        // ---------------- phase 2: aH ----------------
#pragma unroll
        for (int il = 0; il < 2; ++il)
#pragma unroll
            for (int kh = 0; kh < 2; ++kh)
                af[il * 2 + kh] = *(const f16x8*)(R +
                    (unsigned)((kh * 4 + q) * BM + mb + (2 + il) * 16 + m16) * 16u);
        if (st) {
            gl_lds16(sB + ks,      W + ASZ + dstT);
            gl_lds16(sB + ks + 32, W + ASZ + 8192 + dstT);
        }
        asm volatile("s_barrier" ::: "memory");
        asm volatile("s_waitcnt lgkmcnt(0)" ::: "memory");
        __builtin_amdgcn_s_setprio(1);
#pragma unroll
        for (int il = 0; il < 2; ++il)
#pragma unroll
            for (int jl = 0; jl < 2; ++jl)
#pragma unroll
                for (int kh = 0; kh < 2; ++kh)
                    acc[2 + il][2 + jl] = __builtin_amdgcn_mfma_f32_16x16x32_f16(
                        af[il * 2 + kh], bH[jl * 2 + kh], acc[2 + il][2 + jl], 0, 0, 0);
        __builtin_amdgcn_s_setprio(0);
        asm volatile("s_barrier" ::: "memory");

        // ---------------- phase 3: aH x bL (no reads) ----------------
        __builtin_amdgcn_s_setprio(1);
#pragma unroll
        for (int il = 0; il < 2; ++il)
#pragma unroll
            for (int jl = 0; jl < 2; ++jl)
#pragma unroll
                for (int kh = 0; kh < 2; ++kh)
                    acc[2 + il][jl] = __builtin_amdgcn_mfma_f32_16x16x32_f16(
                        af[il * 2 + kh], bL[jl * 2 + kh], acc[2 + il][jl], 0, 0, 0);
        __builtin_amdgcn_s_setprio(0);
        // guarantee tile k+1 (staged last iteration) has landed; the 6 loads
        // for tile k+2 issued THIS iteration stay in flight (counted wait).
        if (st)
            asm volatile("s_waitcnt vmcnt(6)" ::: "memory");
        else
            asm volatile("s_waitcnt vmcnt(0)" ::: "memory");
        asm volatile("s_barrier" ::: "memory");

        cur += BUFSZ;
        if (cur >= LDSTOT) cur -= LDSTOT;
    }

    // epilogue (verified C/D mapping: col=lane&15, row=q*4+rix)
#pragma unroll
    for (int i = 0; i < 4; ++i)
#pragma unroll
        for (int j = 0; j < 4; ++j) {
            int row = m0 + mb + i * 16 + q * 4;
            int col = n0 + nb + j * 16 + m16;
#pragma unroll
            for (int rix = 0; rix < 4; ++rix) {
                float v = acc[i][j][rix];
                size_t o = (size_t)(row + rix) * N + col;
                if constexpr (EPI == 0) {
                    outb[o] = (OT)gelu_f(v);
                } else {
                    outb[o] = (OT)(v + addsrc[o]);
                }
            }
        }
}

extern "C" void kernel_launch(void* const* d_in, const int* in_sizes, int n_in,
                              void* d_out, int out_size, void* d_ws, size_t ws_size,
                              hipStream_t stream) {
    const float* x    = (const float*)d_in[0];
    const float* rw   = (const float*)d_in[1];
    const int*   nf4  = (const int*)d_in[2];
    const float* mean = (const float*)d_in[3];
    const float* stdv = (const float*)d_in[4];
    const float* cb   = (const float*)d_in[5];
    const float* w1   = (const float*)d_in[6];
    const float* w2   = (const float*)d_in[7];
    float* out = (float*)d_out;

    char* ws = (char*)d_ws;
    float* probs      = (float*)ws;                          // 128 KB
    float* moe        = (float*)(ws + 131072);               // 32 MB
    _Float16* xh      = (_Float16*)(ws + 33685504);          // 16 MB  [NTOK,H]
    _Float16* w1t     = (_Float16*)(ws + 50462720);          // 32 MB  [DFF,H]
    _Float16* w2t     = (_Float16*)(ws + 84017152);          // 32 MB  [H,DFF]
    _Float16* hid     = (_Float16*)(ws + 117571584);         // 64 MB  [NTOK,DFF]

    router_cast_kernel<<<NTOK, 256, 0, stream>>>(x, rw, probs, xh);
    transpose_cast_kernel<<<dim3(DFF / 32, H / 32), 256, 0, stream>>>(w1, w1t, H, DFF);
    transpose_cast_kernel<<<dim3(H / 32, DFF / 32), 256, 0, stream>>>(w2, w2t, DFF, H);
    moe_kernel<<<NTOK, 256, 0, stream>>>(nf4, mean, stdv, cb, probs, moe);
    // hidden = gelu(x @ w1): 256x128 tiles, grid 16x64 -> 1024 blocks (bwShift=3)
    gemm256_kernel<0, _Float16><<<1024, 512, 0, stream>>>(xh, w1t, nullptr, hid, H, DFF, 3);
    // out = moe + hidden @ w2: 256x128 tiles, grid 16x16 -> 256 blocks (bwShift=1)
    gemm256_kernel<1, float><<<256, 512, 0, stream>>>(hid, w2t, moe, out, DFF, H, 1);
}

// Round 3
// 790.625 us; speedup vs baseline: 1.1041x; 1.1041x over previous
//
#include <hip/hip_runtime.h>
#include <hip/hip_bf16.h>
#include <hip/hip_fp16.h>

#define H 2048
#define E 8
#define DFF 8192
#define NTOK 4096
#define NB 4  // H/512 scale blocks

typedef _Float16 f16x8 __attribute__((ext_vector_type(8)));
typedef float f32x4 __attribute__((ext_vector_type(4)));

#define AS1 __attribute__((address_space(1)))
#define AS3 __attribute__((address_space(3)))

__device__ __forceinline__ void gl_lds16(const void* g, void* l) {
    __builtin_amdgcn_global_load_lds((const AS1 unsigned int*)g,
                                     (AS3 unsigned int*)l, 16, 0, 0);
}

__device__ __forceinline__ float gelu_f(float x) {
    float u = 0.7978845608028654f * x * (1.0f + 0.044715f * x * x);
    float t = fabsf(u);
    float e = __expf(-2.0f * t);
    float th = (1.0f - e) / (1.0f + e);
    th = copysignf(th, u);
    return 0.5f * x * (1.0f + th);
}

// ---------------- router (fp32) + x -> fp16 cast ----------------
__global__ __launch_bounds__(256) void router_cast_kernel(
    const float* __restrict__ x, const float* __restrict__ rw,
    float* __restrict__ probs, _Float16* __restrict__ xh)
{
    int n = blockIdx.x, t = threadIdx.x;
    float acc[E];
#pragma unroll
    for (int e = 0; e < E; ++e) acc[e] = 0.f;
    const float* xr = x + (size_t)n * H;
#pragma unroll
    for (int k = 0; k < H / 256; ++k) {
        int h = t + k * 256;
        float xv = xr[h];
        xh[(size_t)n * H + h] = (_Float16)xv;
        const float4* r4 = reinterpret_cast<const float4*>(rw + (size_t)h * E);
        float4 a = r4[0], b = r4[1];
        acc[0] += xv * a.x; acc[1] += xv * a.y; acc[2] += xv * a.z; acc[3] += xv * a.w;
        acc[4] += xv * b.x; acc[5] += xv * b.y; acc[6] += xv * b.z; acc[7] += xv * b.w;
    }
#pragma unroll
    for (int e = 0; e < E; ++e) {
        float v = acc[e];
#pragma unroll
        for (int o = 32; o > 0; o >>= 1) v += __shfl_down(v, o, 64);
        acc[e] = v;
    }
    __shared__ float red[4][E];
    int wave = t >> 6, lane = t & 63;
    if (lane == 0) {
#pragma unroll
        for (int e = 0; e < E; ++e) red[wave][e] = acc[e];
    }
    __syncthreads();
    if (t == 0) {
        float lg[E];
        float mx = -1e30f;
#pragma unroll
        for (int e = 0; e < E; ++e) {
            lg[e] = red[0][e] + red[1][e] + red[2][e] + red[3][e];
            mx = fmaxf(mx, lg[e]);
        }
        float s = 0.f;
#pragma unroll
        for (int e = 0; e < E; ++e) { lg[e] = expf(lg[e] - mx); s += lg[e]; }
        float inv = 1.f / s;
#pragma unroll
        for (int e = 0; e < E; ++e) {
            float p = lg[e] * inv;
            p = __half2float(__float2half(p));
            probs[(size_t)n * E + e] = p;
        }
    }
}

// ---------------- transpose + cast fp32 [R,C] -> fp16 [C,R] ----------------
__global__ __launch_bounds__(256) void transpose_cast_kernel(
    const float* __restrict__ src, _Float16* __restrict__ dst, int R, int C)
{
    __shared__ float tile[32][33];
    int tx = threadIdx.x & 31, ty = threadIdx.x >> 5;
    int c0 = blockIdx.x * 32, r0 = blockIdx.y * 32;
#pragma unroll
    for (int i = ty; i < 32; i += 8)
        tile[i][tx] = src[(size_t)(r0 + i) * C + c0 + tx];
    __syncthreads();
#pragma unroll
    for (int i = ty; i < 32; i += 8)
        dst[(size_t)(c0 + i) * R + r0 + tx] = (_Float16)tile[tx][i];
}

// ---------------- NF4 dequant + expert mix -> moe (fp32) ----------------
__global__ __launch_bounds__(256) void moe_kernel(
    const int* __restrict__ nf4, const float* __restrict__ mean,
    const float* __restrict__ stdv, const float* __restrict__ cb,
    const float* __restrict__ probs, float* __restrict__ moe)
{
    int n = blockIdx.x, t = threadIdx.x;
    __shared__ float cbl[32];
    __shared__ float ps[E][NB];
    __shared__ float cmean[NB];
    if (t < 16) { float v = cb[t]; cbl[t] = v; cbl[t + 16] = v; }
    else if (t >= 32 && t < 64) {
        int e = (t - 32) >> 2, b = t & 3;
        ps[e][b] = probs[(size_t)n * E + e] * stdv[((size_t)n * E + e) * NB + b];
    } else if (t >= 64 && t < 68) {
        int b = t - 64; float s = 0.f;
        for (int e = 0; e < E; ++e)
            s += probs[(size_t)n * E + e] * mean[((size_t)n * E + e) * NB + b];
        cmean[b] = s;
    }
    __syncthreads();
    int cboff = (t & 1) << 4;
    const int* w = nf4 + (size_t)n * (E * H / 2);
    float2* outp = reinterpret_cast<float2*>(moe + (size_t)n * H);
#pragma unroll
    for (int k = 0; k < 4; ++k) {
        int j = t + k * 256;
        float psr[E];
#pragma unroll
        for (int e = 0; e < E; ++e) psr[e] = ps[e][k];
        float cm = cmean[k];
        float aL = cm, aH = cm;
#pragma unroll
        for (int e = 0; e < E; ++e) {
            int word = w[e * (H / 2) + j];
            aL += psr[e] * cbl[(word & 15) + cboff];
            aH += psr[e] * cbl[((word >> 4) & 15) + cboff];
        }
        outp[j] = make_float2(aL, aH);
    }
}

// ---------------- fp16 MFMA GEMM: m201-geometry 8-phase 256x256 ----------
// C = A[M,K] * Bt[N,K]^T.  512 thr / 8 waves (2M x 4N, per-wave 128x64,
// acc[8][4]).  BK=64, LDS = 2 bufs x (A 32KB + B 32KB) = 128 KB.
// k-seg-major LDS layout (verified bank-conflict-free; global_load_lds
// writes linearly, per-lane GLOBAL address provides the permutation).
// Iteration = 2 K-tiles (t0 in buf0 via p1-p4, t1 in buf1 via p5-p8).
// Every phase stages one 16KB chunk (2 x gl_lds16); staging slots:
//   p4-p7 -> tile t0+2 (buf0);  p8,p1',p2',p3' -> tile t1+2 (buf1)
// so each chunk has 2-5 phases of flight.  Counted vmcnt(2) ONLY at p4/p8
// (before that phase's final barrier): drains the 8 loads of the tile the
// NEXT phase reads, leaves this phase's 2 in flight; final barrier then
// publishes other waves' stages, so the next phase's PRE-barrier ds_reads
// are safe.  Quadrants Gray-ordered (iL,jL)->(iL,jH)->(iH,jH)->(iH,jL):
// read phases carry 12/4/8/0 ds_read_b128; 16 MFMA per phase per wave
// wrapped in s_setprio.
// EPI 0: out = f16(gelu(acc)).
// EPI 1: split-K pair: ks==0 -> out = acc + addsrc (float); ks==1 -> aux = acc.
template <int EPI, int MAP>
__global__ __launch_bounds__(512, 2) void gemm8p_kernel(
    const _Float16* __restrict__ A, const _Float16* __restrict__ Bt,
    const float* __restrict__ addsrc, void* __restrict__ outv,
    float* __restrict__ aux, int K, int LDK, int N)
{
    __shared__ uint4 lds_u4[131072 / 16];   // 128 KB
    char* lds = (char*)lds_u4;
    char* R0 = lds;
    char* R1 = lds + 65536;

    int t = threadIdx.x;
    int id = blockIdx.x;
    int xcd = id & 7, chunk = id >> 3;
    int by, bx, ks = 0;
    if constexpr (MAP == 0) {
        // GEMM1: 512 blocks; per XCD an 8by x 8bx patch (16 MB unique/XCD)
        by = (xcd & 1) * 8 + (chunk & 7);
        bx = (xcd >> 1) * 8 + (chunk >> 3);
    } else {
        // GEMM2 split-K2: 256 blocks; per XCD 4by x 4bx x 2ks (32 MB/XCD)
        by = (xcd >> 1) * 4 + (chunk & 3);
        bx = (xcd & 1) * 4 + ((chunk >> 2) & 3);
        ks = chunk >> 4;
    }
    int m0 = by * 256, n0 = bx * 256;
    int koff = ks * K;

    const unsigned short* sA = (const unsigned short*)A
        + (size_t)(m0 + (t & 255)) * LDK + koff + (t >> 8) * 8;
    const unsigned short* sB = (const unsigned short*)Bt
        + (size_t)(n0 + (t & 255)) * LDK + koff + (t >> 8) * 8;
    unsigned dstT = (unsigned)t * 16;

    int lane = t & 63, wave = t >> 6;
    int wr = wave >> 2, wc = wave & 3;      // 2M x 4N
    int mb = wr * 128, nb = wc * 64;
    int q = lane >> 4, m16 = lane & 15;

    unsigned aBase = (unsigned)(mb + m16) * 16u;
    unsigned bBase = 32768u + (unsigned)(nb + m16) * 16u;

    f32x4 acc[8][4] = {};
    f16x8 af[8], bL[4], bH[4];

#define STG_A(Wb, T, s) do { \
    gl_lds16(sA + (size_t)(T) * 64 + (s) * 16,      (Wb) + (s) * 8192 + dstT); \
    gl_lds16(sA + (size_t)(T) * 64 + (s) * 16 + 16, (Wb) + (s) * 8192 + 8192 + dstT); } while (0)
#define STG_B(Wb, T, s) do { \
    gl_lds16(sB + (size_t)(T) * 64 + (s) * 16,      (Wb) + 32768 + (s) * 8192 + dstT); \
    gl_lds16(sB + (size_t)(T) * 64 + (s) * 16 + 16, (Wb) + 32768 + (s) * 8192 + 8192 + dstT); } while (0)
#define RD_A(Rb, ih) do { \
    _Pragma("unroll") for (int il = 0; il < 4; ++il) \
    _Pragma("unroll") for (int kh = 0; kh < 2; ++kh) \
        af[il * 2 + kh] = *(const f16x8*)((Rb) + aBase + \
            (unsigned)(kh * 16384 + q * 4096 + (ih) * 1024 + il * 256)); } while (0)
#define RD_B(Rb, jh, dst) do { \
    _Pragma("unroll") for (int jl = 0; jl < 2; ++jl) \
    _Pragma("unroll") for (int kh = 0; kh < 2; ++kh) \
        dst[jl * 2 + kh] = *(const f16x8*)((Rb) + bBase + \
            (unsigned)(kh * 16384 + q * 4096 + (jh) * 512 + jl * 256)); } while (0)
#define MMQ(ih, bfr, j0) do { \
    __builtin_amdgcn_s_setprio(1); \
    _Pragma("unroll") for (int il = 0; il < 4; ++il) \
    _Pragma("unroll") for (int jl = 0; jl < 2; ++jl) \
    _Pragma("unroll") for (int kh = 0; kh < 2; ++kh) \
        acc[(ih) * 4 + il][(j0) + jl] = __builtin_amdgcn_mfma_f32_16x16x32_f16( \
            af[il * 2 + kh], bfr[jl * 2 + kh], acc[(ih) * 4 + il][(j0) + jl], 0, 0, 0); \
    __builtin_amdgcn_s_setprio(0); } while (0)
#define BARR  asm volatile("s_barrier" ::: "memory")
#define LGKM0 asm volatile("s_waitcnt lgkmcnt(0)" ::: "memory")

    // prologue: tile 0 fully -> buf0 (8 loads) + tile 1 chunk A01 -> buf1 (2)
    STG_A(R0, 0, 0); STG_A(R0, 0, 2);
    STG_B(R0, 0, 0); STG_B(R0, 0, 2);
    STG_A(R1, 1, 0);
    asm volatile("s_waitcnt vmcnt(2)" ::: "memory");  // tile 0 landed
    BARR;

    int NIT = K / 128;
    for (int i = 0; i < NIT; ++i) {
        int T0 = 2 * i, T1 = 2 * i + 1;
        bool more = (i + 1 < NIT);

        // ---- p1: stage t1.A23->buf1 | read t0 A-iL + B-jL | mfma (iL,jL)
        STG_A(R1, T1, 2);
        RD_A(R0, 0); RD_B(R0, 0, bL);
        BARR; LGKM0;
        MMQ(0, bL, 0);
        BARR;
        // ---- p2: stage t1.B01 | read t0 B-jH | mfma (iL,jH)
        STG_B(R1, T1, 0);
        RD_B(R0, 1, bH);
        BARR; LGKM0;
        MMQ(0, bH, 2);
        BARR;
        // ---- p3: stage t1.B23 | read t0 A-iH | mfma (iH,jH)
        STG_B(R1, T1, 2);
        RD_A(R0, 1);
        BARR; LGKM0;
        MMQ(1, bH, 2);
        BARR;
        // ---- p4: stage t2.A01->buf0 (buf0 reads done at p3) | mfma (iH,jL)
        //      vmcnt(2): drain ALL of t1 (needed p5), keep p4's 2 in flight
        if (more) STG_A(R0, T0 + 2, 0);
        MMQ(1, bL, 0);
        if (more) asm volatile("s_waitcnt vmcnt(2)" ::: "memory");
        else      asm volatile("s_waitcnt vmcnt(0)" ::: "memory");
        BARR;

        // ---- p5: stage t2.A23 | read t1 A-iL + B-jL | mfma (iL,jL)
        if (more) STG_A(R0, T0 + 2, 2);
        RD_A(R1, 0); RD_B(R1, 0, bL);
        BARR; LGKM0;
        MMQ(0, bL, 0);
        BARR;
        // ---- p6: stage t2.B01 | read t1 B-jH | mfma (iL,jH)
        if (more) STG_B(R0, T0 + 2, 0);
        RD_B(R1, 1, bH);
        BARR; LGKM0;
        MMQ(0, bH, 2);
        BARR;
        // ---- p7: stage t2.B23 | read t1 A-iH | mfma (iH,jH)
        if (more) STG_B(R0, T0 + 2, 2);
        RD_A(R1, 1);
        BARR; LGKM0;
        MMQ(1, bH, 2);
        BARR;
        // ---- p8: stage t3.A01->buf1 (buf1 reads done at p7) | mfma (iH,jL)
        //      vmcnt(2): drain ALL of t2 (needed next p1), keep p8's 2
        if (more) STG_A(R1, T1 + 2, 0);
        MMQ(1, bL, 0);
        if (more) asm volatile("s_waitcnt vmcnt(2)" ::: "memory");
        else      asm volatile("s_waitcnt vmcnt(0)" ::: "memory");
        BARR;
    }

    // epilogue (verified C/D mapping: col=lane&15, row=q*4+rix)
#pragma unroll
    for (int i = 0; i < 8; ++i)
#pragma unroll
        for (int j = 0; j < 4; ++j) {
            int row = m0 + mb + i * 16 + q * 4;
            int col = n0 + nb + j * 16 + m16;
#pragma unroll
            for (int rix = 0; rix < 4; ++rix) {
                float v = acc[i][j][rix];
                size_t o = (size_t)(row + rix) * N + col;
                if constexpr (EPI == 0) {
                    ((_Float16*)outv)[o] = (_Float16)gelu_f(v);
                } else {
                    if (ks == 0) ((float*)outv)[o] = v + addsrc[o];
                    else         aux[o] = v;
                }
            }
        }
#undef STG_A
#undef STG_B
#undef RD_A
#undef RD_B
#undef MMQ
#undef BARR
#undef LGKM0
}

// ---------------- split-K combine: out += part ----------------
__global__ __launch_bounds__(256) void combine_kernel(
    float* __restrict__ out, const float* __restrict__ part)
{
    size_t base = (size_t)blockIdx.x * 256 + threadIdx.x;
    const float4* p4 = (const float4*)part;
    float4* o4 = (float4*)out;
#pragma unroll
    for (int s = 0; s < 4; ++s) {
        size_t i = base + (size_t)s * 524288;   // 2048*256
        float4 a = o4[i], b = p4[i];
        o4[i] = make_float4(a.x + b.x, a.y + b.y, a.z + b.z, a.w + b.w);
    }
}

extern "C" void kernel_launch(void* const* d_in, const int* in_sizes, int n_in,
                              void* d_out, int out_size, void* d_ws, size_t ws_size,
                              hipStream_t stream) {
    const float* x    = (const float*)d_in[0];
    const float* rw   = (const float*)d_in[1];
    const int*   nf4  = (const int*)d_in[2];
    const float* mean = (const float*)d_in[3];
    const float* stdv = (const float*)d_in[4];
    const float* cb   = (const float*)d_in[5];
    const float* w1   = (const float*)d_in[6];
    const float* w2   = (const float*)d_in[7];
    float* out = (float*)d_out;

    char* ws = (char*)d_ws;
    float* probs      = (float*)ws;                          // 128 KB
    float* moe        = (float*)(ws + 131072);               // 32 MB
    _Float16* xh      = (_Float16*)(ws + 33685504);          // 16 MB  [NTOK,H]
    _Float16* w1t     = (_Float16*)(ws + 50462720);          // 32 MB  [DFF,H]
    _Float16* w2t     = (_Float16*)(ws + 84017152);          // 32 MB  [H,DFF]
    _Float16* hid     = (_Float16*)(ws + 117571584);         // 64 MB  [NTOK,DFF]
    // split-K partial buffer overlays w1t (dead after GEMM1): 32 MB fp32
    float* pbuf       = (float*)(ws + 50462720);

    router_cast_kernel<<<NTOK, 256, 0, stream>>>(x, rw, probs, xh);
    transpose_cast_kernel<<<dim3(DFF / 32, H / 32), 256, 0, stream>>>(w1, w1t, H, DFF);
    transpose_cast_kernel<<<dim3(H / 32, DFF / 32), 256, 0, stream>>>(w2, w2t, DFF, H);
    moe_kernel<<<NTOK, 256, 0, stream>>>(nf4, mean, stdv, cb, probs, moe);
    // hidden = gelu(x @ w1): 256x256 tiles, grid 16x32 -> 512 blocks (2 rounds)
    gemm8p_kernel<0, 0><<<512, 512, 0, stream>>>(xh, w1t, nullptr, (void*)hid,
                                                 nullptr, H, H, DFF);
    // out = moe + hidden @ w2, split-K=2: 256 blocks (1/CU)
    //   ks0 -> out (= acc + moe), ks1 -> pbuf
    gemm8p_kernel<1, 1><<<256, 512, 0, stream>>>(hid, w2t, moe, (void*)out,
                                                 pbuf, DFF / 2, DFF, H);
    // out += pbuf
    combine_kernel<<<2048, 256, 0, stream>>>(out, pbuf);
}